// Round 3
// baseline (84.502 us; speedup 1.0000x reference)
//
#include <hip/hip_runtime.h>
#include <math.h>

#define NS 256
#define EMB 120
#define MODES 16
#define NPH 8

typedef float v2f __attribute__((ext_vector_type(2)));

// complex mul
__device__ __forceinline__ v2f cmul(v2f a, v2f b) {
    v2f axx = {a.x, a.x};
    v2f nyy = {-a.y, a.y};
    v2f byx = {b.y, b.x};
    return axx * b + nyy * byx;   // {ax*bx - ay*by, ax*by + ay*bx}
}
// r = conj(a)*b + c
__device__ __forceinline__ v2f cfma_conj(v2f a, v2f b, v2f c) {
    v2f axx = {a.x, a.x};
    v2f pyy = {a.y, -a.y};
    v2f byx = {b.y, b.x};
    return axx * b + (pyy * byx + c);
}

// Cross-lane xor within quad via DPP quad_perm (VALU, not LDS pipe).
// xor1: [1,0,3,2] -> ctrl 0xB1 ; xor2: [2,3,0,1] -> ctrl 0x4E
__device__ __forceinline__ float dpp_xor1(float x) {
    return __builtin_bit_cast(float,
        __builtin_amdgcn_mov_dpp(__builtin_bit_cast(int, x), 0xB1, 0xF, 0xF, true));
}
__device__ __forceinline__ float dpp_xor2(float x) {
    return __builtin_bit_cast(float,
        __builtin_amdgcn_mov_dpp(__builtin_bit_cast(int, x), 0x4E, 0xF, 0xF, true));
}

// Fused kernel v2. Per tile-pair block: efficient prologue (W staged once,
// coalesced, into LDS; register-blocked GEMM; libm sincos kept for accuracy;
// V-build as verified in round 1), then the verified round-0 permanent core
// (64-term Gray ladder, 4 lanes/pair). One launch: no inter-kernel gap, no
// Vws global round-trip, prologue runs at 8 waves/CU instead of emb's 2.
__global__ __launch_bounds__(256, 2) void fused_perm_kernel(
    const float* __restrict__ x, const float* __restrict__ W,
    const float* __restrict__ bias, float* __restrict__ out_emb,
    float* __restrict__ outK)
{
    __shared__ __align__(16) float2 sva[8][132];
    __shared__ __align__(16) float2 svb[8][132];
    __shared__ __align__(16) float  xls[16][64];       // staged x rows
    __shared__ float  embl[16][120];                   // sigmoid outputs
    __shared__ __align__(16) float  angl[16][61][4];   // ct,st,ex,ey per (slot, block)
    __shared__ __align__(16) float  wld[120][68];      // W rows, pitch-68 (bank spread)

    // triangular decode: blockIdx -> (ta, tb), ta <= tb  (32 tiles of 8 samples)
    const int L = blockIdx.x;
    int t = (int)((65.0f - sqrtf(4225.0f - 8.0f * (float)L)) * 0.5f);
    while (t * (65 - t) / 2 > L) --t;
    while ((t + 1) * (65 - (t + 1)) / 2 <= L) ++t;
    const int ta = t;
    const int tb = ta + (L - t * (65 - t) / 2);

    const int tid = threadIdx.x;

    // ---- P1a: stage the 16 slots' x rows (slot 0..7 = tile a, 8..15 = tile b) ----
    {
        const int i  = tid >> 4;          // slot
        const int q  = tid & 15;          // float4 within row
        const int si = (i < 8) ? (ta * 8 + i) : (tb * 8 + (i - 8));
        const float4 xv = ((const float4*)(x + (size_t)si * 64))[q];
        *(float4*)&xls[i][q * 4] = xv;
    }
    // ---- P1b: stage W coalesced into LDS (1920 float4) ----
    {
        const float4* Wg = (const float4*)W;
        #pragma unroll
        for (int r = 0; r < 8; ++r) {
            const int idx = r * 256 + tid;          // 0..2047
            if (idx < 1920) {
                const int j = idx >> 4;
                const int q = idx & 15;
                const float4 w = Wg[idx];
                *(float4*)&wld[j][q * 4] = w;
            }
        }
    }
    __syncthreads();

    // ---- P2: emb = sigmoid(x @ W.T + b), register-blocked ----
    // lane owns output column j (W row cached in 64 VGPRs, read once from LDS);
    // loops over 8 sample slots with broadcast x reads.
    // fmaf chain order identical to the original kernel (bit-identical).
    {
        const int j  = tid & 127;
        const int ig = tid >> 7;          // slot group: 0 -> slots 0..7, 1 -> 8..15
        if (j < EMB) {
            float4 wr[16];
            #pragma unroll
            for (int k4 = 0; k4 < 16; ++k4)
                wr[k4] = *(const float4*)&wld[j][k4 * 4];
            const float bj = bias[j];
            #pragma unroll
            for (int ii = 0; ii < 8; ++ii) {
                const int i = ig * 8 + ii;
                float acc = bj;
                #pragma unroll
                for (int k4 = 0; k4 < 16; ++k4) {
                    const float4 xv = *(const float4*)&xls[i][k4 * 4];
                    acc = fmaf(xv.x, wr[k4].x, acc);
                    acc = fmaf(xv.y, wr[k4].y, acc);
                    acc = fmaf(xv.z, wr[k4].z, acc);
                    acc = fmaf(xv.w, wr[k4].w, acc);
                }
                const float e = 1.0f / (1.0f + expf(-acc));
                embl[i][j] = e;
                if (ta == tb && i < 8)
                    out_emb[(size_t)(ta * 8 + i) * EMB + j] = e;
            }
        }
    }
    __syncthreads();

    // ---- P3: angles: 16 slots x 60 blocks = 960 tasks over 256 threads ----
    #pragma unroll
    for (int r = 0; r < 4; ++r) {
        const int idx = tid + 256 * r;
        if (idx < 960) {
            const int i = idx / 60;
            const int b = idx - i * 60;
            const float th = embl[i][2 * b]     * 1.57079632679489662f;  // pi/2
            const float ph = embl[i][2 * b + 1] * 6.28318530717958648f;  // 2*pi
            float st, ct, sp, cp;
            sincosf(th, &st, &ct);
            sincosf(ph, &sp, &cp);
            angl[i][b][0] = ct; angl[i][b][1] = st;
            angl[i][b][2] = cp; angl[i][b][3] = sp;
        }
    }
    __syncthreads();

    // ---- P4: build V columns: 16 slots x 8 cols = 128 builder threads ----
    if (tid < 128) {
        const int i = tid >> 3;
        const int c = tid & 7;
        float2 u[MODES];
        #pragma unroll
        for (int m = 0; m < MODES; ++m) {
            u[m].x = (m == c) ? 1.0f : 0.0f;
            u[m].y = 0.0f;
        }
        int bi = 0;
        #pragma unroll
        for (int d = 0; d < 8; ++d) {
            const int off = d & 1;
            const int nb = 8 - off;
            #pragma unroll
            for (int k = 0; k < nb; ++k) {
                const float4 a4 = *(const float4*)&angl[i][bi][0];
                const float ct = a4.x, st = a4.y, ex = a4.z, ey = a4.w;
                ++bi;
                const int r0 = off + 2 * k;
                float2 u0 = u[r0], u1 = u[r0 + 1];
                float2 n0, n1;
                n0.x = ex * ct * u0.x - ey * ct * u0.y - st * u1.x;
                n0.y = ex * ct * u0.y + ey * ct * u0.x - st * u1.y;
                n1.x = ex * st * u0.x - ey * st * u0.y + ct * u1.x;
                n1.y = ex * st * u0.y + ey * st * u0.x + ct * u1.y;
                u[r0] = n0; u[r0 + 1] = n1;
            }
        }
        float2* dst = (i < 8) ? &sva[i][0] : &svb[i - 8][0];
        #pragma unroll
        for (int m = 0; m < MODES; ++m)
            dst[m * 8 + c] = u[m];   // layout: [row][m*8 + col], matches G-build reads
    }
    __syncthreads();

    // ---- permanent core: verified round-0 version (64 terms, 4 lanes/pair) ----
    const int p   = tid >> 2;    // pair 0..63 (quad-aligned lanes)
    const int sub = tid & 3;
    const int h   = sub & 1;     // row half
    const int e   = sub >> 1;    // delta7 half
    const int pa  = p >> 3;
    const int pb  = p & 7;

    // ---- build own 2 rows: rows 4h+2e, 4h+2e+1 of G = Va^H Vb ----
    v2f Go[2][8];
    #pragma unroll
    for (int i = 0; i < 2; ++i)
        #pragma unroll
        for (int j = 0; j < 8; ++j) Go[i][j] = (v2f){0.f, 0.f};

    #pragma unroll 2
    for (int m = 0; m < 16; ++m) {
        float4 va4 = *(const float4*)&sva[pa][m * 8 + 4 * h + 2 * e];
        v2f a0 = {va4.x, va4.y};
        v2f a1 = {va4.z, va4.w};
        v2f vb[8];
        #pragma unroll
        for (int jj = 0; jj < 4; ++jj) {
            float4 b4 = *(const float4*)&svb[pb][m * 8 + 2 * jj];
            vb[2 * jj]     = (v2f){b4.x, b4.y};
            vb[2 * jj + 1] = (v2f){b4.z, b4.w};
        }
        #pragma unroll
        for (int j = 0; j < 8; ++j) {
            Go[0][j] = cfma_conj(a0, vb[j], Go[0][j]);
            Go[1][j] = cfma_conj(a1, vb[j], Go[1][j]);
        }
    }

    // ---- exchange 2 rows with delta-partner (xor 2) via DPP ----
    v2f Gp[2][8];
    #pragma unroll
    for (int i = 0; i < 2; ++i)
        #pragma unroll
        for (int j = 0; j < 8; ++j) {
            Gp[i][j].x = dpp_xor2(Go[i][j].x);
            Gp[i][j].y = dpp_xor2(Go[i][j].y);
        }

    // ---- rs init: delta = (+1,...,+1, sgn_e) ----
    const float sgn = 1.0f - 2.0f * (float)e;
    const v2f sgnv = {sgn, sgn};
    v2f rs[4];
    #pragma unroll
    for (int r = 0; r < 2; ++r) {
        {
            v2f s = ((Go[r][0] + Go[r][1]) + (Go[r][2] + Go[r][3]))
                  + ((Go[r][4] + Go[r][5]) + Go[r][6]);
            rs[r] = sgnv * Go[r][7] + s;
        }
        {
            v2f s = ((Gp[r][0] + Gp[r][1]) + (Gp[r][2] + Gp[r][3]))
                  + ((Gp[r][4] + Gp[r][5]) + Gp[r][6]);
            rs[2 + r] = sgnv * Gp[r][7] + s;
        }
    }

    v2f acc;

#define TREE(OUT) do {                                                \
        v2f t01 = cmul(rs[0], rs[1]);                                 \
        v2f t23 = cmul(rs[2], rs[3]);                                 \
        v2f half_ = cmul(t01, t23);                                   \
        v2f oth;                                                      \
        oth.x = dpp_xor1(half_.x);                                    \
        oth.y = dpp_xor1(half_.y);                                    \
        OUT = cmul(half_, oth);                                       \
    } while (0)

#define UPD(J, S) do {                                                \
        const v2f sv = {(S), (S)};                                    \
        rs[0] = sv * Go[0][J] + rs[0];                                \
        rs[1] = sv * Go[1][J] + rs[1];                                \
        rs[2] = sv * Gp[0][J] + rs[2];                                \
        rs[3] = sv * Gp[1][J] + rs[3];                                \
    } while (0)

#define TERM(TS) do {                                                 \
        v2f fullp; TREE(fullp);                                       \
        const v2f tv = {(TS), (TS)};                                  \
        acc = tv * fullp + acc;                                       \
    } while (0)

    TREE(acc);                              // t=0, sign +
    UPD(1, -2.f); TERM(-1.f);               // t=1
    UPD(2, -2.f); TERM( 1.f);               // t=2
    UPD(1,  2.f); TERM(-1.f);               // t=3
    UPD(3, -2.f); TERM( 1.f);               // t=4
    UPD(1, -2.f); TERM(-1.f);               // t=5
    UPD(2,  2.f); TERM( 1.f);               // t=6
    UPD(1,  2.f); TERM(-1.f);               // t=7
    UPD(4, -2.f); TERM( 1.f);               // t=8
    UPD(1, -2.f); TERM(-1.f);               // t=9
    UPD(2, -2.f); TERM( 1.f);               // t=10
    UPD(1,  2.f); TERM(-1.f);               // t=11
    UPD(3,  2.f); TERM( 1.f);               // t=12
    UPD(1, -2.f); TERM(-1.f);               // t=13
    UPD(2,  2.f); TERM( 1.f);               // t=14
    UPD(1,  2.f); TERM(-1.f);               // t=15
    UPD(5, -2.f); TERM( 1.f);               // t=16
    UPD(1, -2.f); TERM(-1.f);               // t=17
    UPD(2, -2.f); TERM( 1.f);               // t=18
    UPD(1,  2.f); TERM(-1.f);               // t=19
    UPD(3, -2.f); TERM( 1.f);               // t=20
    UPD(1, -2.f); TERM(-1.f);               // t=21
    UPD(2,  2.f); TERM( 1.f);               // t=22
    UPD(1,  2.f); TERM(-1.f);               // t=23
    UPD(4,  2.f); TERM( 1.f);               // t=24
    UPD(1, -2.f); TERM(-1.f);               // t=25
    UPD(2, -2.f); TERM( 1.f);               // t=26
    UPD(1,  2.f); TERM(-1.f);               // t=27
    UPD(3,  2.f); TERM( 1.f);               // t=28
    UPD(1, -2.f); TERM(-1.f);               // t=29
    UPD(2,  2.f); TERM( 1.f);               // t=30
    UPD(1,  2.f); TERM(-1.f);               // t=31
    UPD(6, -2.f); TERM( 1.f);               // t=32
    UPD(1, -2.f); TERM(-1.f);               // t=33
    UPD(2, -2.f); TERM( 1.f);               // t=34
    UPD(1,  2.f); TERM(-1.f);               // t=35
    UPD(3, -2.f); TERM( 1.f);               // t=36
    UPD(1, -2.f); TERM(-1.f);               // t=37
    UPD(2,  2.f); TERM( 1.f);               // t=38
    UPD(1,  2.f); TERM(-1.f);               // t=39
    UPD(4, -2.f); TERM( 1.f);               // t=40
    UPD(1, -2.f); TERM(-1.f);               // t=41
    UPD(2, -2.f); TERM( 1.f);               // t=42
    UPD(1,  2.f); TERM(-1.f);               // t=43
    UPD(3,  2.f); TERM( 1.f);               // t=44
    UPD(1, -2.f); TERM(-1.f);               // t=45
    UPD(2,  2.f); TERM( 1.f);               // t=46
    UPD(1,  2.f); TERM(-1.f);               // t=47
    UPD(5,  2.f); TERM( 1.f);               // t=48
    UPD(1, -2.f); TERM(-1.f);               // t=49
    UPD(2, -2.f); TERM( 1.f);               // t=50
    UPD(1,  2.f); TERM(-1.f);               // t=51
    UPD(3, -2.f); TERM( 1.f);               // t=52
    UPD(1, -2.f); TERM(-1.f);               // t=53
    UPD(2,  2.f); TERM( 1.f);               // t=54
    UPD(1,  2.f); TERM(-1.f);               // t=55
    UPD(4,  2.f); TERM( 1.f);               // t=56
    UPD(1, -2.f); TERM(-1.f);               // t=57
    UPD(2, -2.f); TERM( 1.f);               // t=58
    UPD(1,  2.f); TERM(-1.f);               // t=59
    UPD(3,  2.f); TERM( 1.f);               // t=60
    UPD(1, -2.f); TERM(-1.f);               // t=61
    UPD(2,  2.f); TERM( 1.f);               // t=62
    UPD(1,  2.f); TERM(-1.f);               // t=63
#undef UPD
#undef TERM
#undef TREE

    // fold delta7 sign, then combine the two delta-halves (xor 2, DPP)
    float ax = sgn * acc.x, ay = sgn * acc.y;
    ax += dpp_xor2(ax);
    ay += dpp_xor2(ay);

    if (sub == 0) {
        const int a = ta * 8 + pa;
        const int b = tb * 8 + pb;
        float K = fmaf(ax, ax, ay * ay) * (1.0f / 16384.0f);
        if (a == b) K = 1.0f;
        outK[a * 256 + b] = K;
        outK[b * 256 + a] = K;   // Hermitian symmetry
    }
}

extern "C" void kernel_launch(void* const* d_in, const int* in_sizes, int n_in,
                              void* d_out, int out_size, void* d_ws, size_t ws_size,
                              hipStream_t stream) {
    const float* x    = (const float*)d_in[0];   // 256*64
    const float* W    = (const float*)d_in[1];   // 120*64
    const float* bias = (const float*)d_in[2];   // 120
    float* out     = (float*)d_out;
    float* out_emb = out;              // 256*120
    float* outK    = out + NS * EMB;   // 256*256
    (void)d_ws; (void)ws_size; (void)in_sizes; (void)n_in;

    fused_perm_kernel<<<528, 256, 0, stream>>>(x, W, bias, out_emb, outK);
}

// Round 4
// 76.693 us; speedup vs baseline: 1.1018x; 1.1018x over previous
//
#include <hip/hip_runtime.h>
#include <math.h>

#define NS 256
#define EMB 120
#define NBLK 60
#define MODES 16
#define NPH 8

typedef float v2f __attribute__((ext_vector_type(2)));

// complex mul
__device__ __forceinline__ v2f cmul(v2f a, v2f b) {
    v2f axx = {a.x, a.x};
    v2f nyy = {-a.y, a.y};
    v2f byx = {b.y, b.x};
    return axx * b + nyy * byx;   // {ax*bx - ay*by, ax*by + ay*bx}
}
// r = conj(a)*b + c
__device__ __forceinline__ v2f cfma_conj(v2f a, v2f b, v2f c) {
    v2f axx = {a.x, a.x};
    v2f pyy = {a.y, -a.y};
    v2f byx = {b.y, b.x};
    return axx * b + (pyy * byx + c);
}

// Cross-lane xor within quad via DPP quad_perm (VALU, not LDS pipe).
// xor1: [1,0,3,2] -> ctrl 0xB1 ; xor2: [2,3,0,1] -> ctrl 0x4E
__device__ __forceinline__ float dpp_xor1(float x) {
    return __builtin_bit_cast(float,
        __builtin_amdgcn_mov_dpp(__builtin_bit_cast(int, x), 0xB1, 0xF, 0xF, true));
}
__device__ __forceinline__ float dpp_xor2(float x) {
    return __builtin_bit_cast(float,
        __builtin_amdgcn_mov_dpp(__builtin_bit_cast(int, x), 0x4E, 0xF, 0xF, true));
}

// Kernel A v2: same structure as the round-0 baseline, but W is staged into
// LDS with COALESCED float4 global reads before the GEMM phase. The round-0
// version had lane t read W + t*64 + k: adjacent lanes 256 B apart, so every
// one of the 64 unrolled loads touched ~120 distinct cache lines (serialized
// L1 transactions, 1 block/CU -> no overlap). Removing exactly this pattern
// inside the fused kernel was worth -24 us (R1 -> R3).
// wld pitch 65: GEMM read bank = (t*65+k)%32 = (t+k)%32 -> 2 lanes/bank (free).
// fmaf chain order unchanged (k ascending) -> bit-identical results.
__global__ __launch_bounds__(128) void emb_v_kernel(
    const float* __restrict__ x, const float* __restrict__ W,
    const float* __restrict__ bias, float* __restrict__ out_emb,
    float2* __restrict__ Vws)
{
    const int s = blockIdx.x;
    const int t = threadIdx.x;
    __shared__ float wld[EMB][65];    // W rows, pitch 65 (bank-conflict-free reads)
    __shared__ float xls[64];         // staged x row
    __shared__ float emb[EMB];
    __shared__ float ctA[NBLK], stA[NBLK], exA[NBLK], eyA[NBLK];

    // stage W coalesced: 1920 float4 over 128 threads = 15 each.
    {
        const float4* Wg = (const float4*)W;
        #pragma unroll
        for (int r = 0; r < 15; ++r) {
            const int idx = r * 128 + t;      // 0..1919
            const int j = idx >> 4;           // W row
            const int q = idx & 15;           // float4 within row
            const float4 w = Wg[idx];
            // pitch-65 rows are not 16B-aligned -> scalar stores
            wld[j][q * 4 + 0] = w.x;
            wld[j][q * 4 + 1] = w.y;
            wld[j][q * 4 + 2] = w.z;
            wld[j][q * 4 + 3] = w.w;
        }
    }
    // stage x row (16 float4)
    if (t < 16) {
        const float4 xv = ((const float4*)(x + (size_t)s * 64))[t];
        *(float4*)&xls[t * 4] = xv;
    }
    __syncthreads();

    if (t < EMB) {
        float acc = bias[t];
        #pragma unroll
        for (int k = 0; k < 64; ++k) acc = fmaf(xls[k], wld[t][k], acc);
        float e = 1.0f / (1.0f + expf(-acc));
        emb[t] = e;
        out_emb[s * EMB + t] = e;
    }
    __syncthreads();

    if (t < NBLK) {
        float th = emb[2 * t]     * 1.57079632679489662f;  // pi/2
        float ph = emb[2 * t + 1] * 6.28318530717958648f;  // 2*pi
        float st, ct, sp, cp;
        sincosf(th, &st, &ct);
        sincosf(ph, &sp, &cp);
        ctA[t] = ct; stA[t] = st; exA[t] = cp; eyA[t] = sp;
    }
    __syncthreads();

    if (t < NPH) {
        const int c = t;  // column 0..7
        float2 u[MODES];
        #pragma unroll
        for (int m = 0; m < MODES; ++m) {
            u[m].x = (m == c) ? 1.0f : 0.0f;
            u[m].y = 0.0f;
        }
        int bi = 0;
        #pragma unroll
        for (int d = 0; d < 8; ++d) {
            const int off = d & 1;
            const int nb = 8 - off;
            #pragma unroll
            for (int k = 0; k < nb; ++k) {
                float ct = ctA[bi], st = stA[bi], ex = exA[bi], ey = eyA[bi];
                ++bi;
                const int r0 = off + 2 * k;
                float2 u0 = u[r0], u1 = u[r0 + 1];
                float2 n0, n1;
                n0.x = ex * ct * u0.x - ey * ct * u0.y - st * u1.x;
                n0.y = ex * ct * u0.y + ey * ct * u0.x - st * u1.y;
                n1.x = ex * st * u0.x - ey * st * u0.y + ct * u1.x;
                n1.y = ex * st * u0.y + ey * st * u0.x + ct * u1.y;
                u[r0] = n0; u[r0 + 1] = n1;
            }
        }
        #pragma unroll
        for (int m = 0; m < MODES; ++m)
            Vws[(s * MODES + m) * NPH + c] = u[m];
    }
}

// Kernel B: byte-identical to the round-0 baseline (best measured total).
// Upper-triangular tiles only (K symmetric). 528 blocks of 8x8 pairs.
// 4 threads/pair = (row-half h) x (delta7-half e); cross-lane via DPP quad_perm.
__global__ __launch_bounds__(256, 2) void perm_kernel(
    const float2* __restrict__ Vws, float* __restrict__ outK)
{
    __shared__ float2 sva[8][132];
    __shared__ float2 svb[8][132];

    // triangular decode: blockIdx -> (ta, tb), ta <= tb
    const int L = blockIdx.x;
    int t = (int)((65.0f - sqrtf(4225.0f - 8.0f * (float)L)) * 0.5f);
    while (t * (65 - t) / 2 > L) --t;
    while ((t + 1) * (65 - (t + 1)) / 2 <= L) ++t;
    const int ta = t;
    const int tb = ta + (L - t * (65 - t) / 2);

    const int tid = threadIdx.x;
    const float4* srcA = (const float4*)(Vws + (size_t)ta * 8 * 128);
    const float4* srcB = (const float4*)(Vws + (size_t)tb * 8 * 128);
    #pragma unroll
    for (int r = 0; r < 2; ++r) {
        int idx = r * 256 + tid;       // 0..511
        int row = idx >> 6;
        int c4  = idx & 63;
        *(float4*)&sva[row][c4 * 2] = srcA[idx];
        *(float4*)&svb[row][c4 * 2] = srcB[idx];
    }
    __syncthreads();

    const int p   = tid >> 2;    // pair 0..63 (quad-aligned lanes)
    const int sub = tid & 3;
    const int h   = sub & 1;     // row half
    const int e   = sub >> 1;    // delta7 half
    const int pa  = p >> 3;
    const int pb  = p & 7;

    // ---- build own 2 rows: rows 4h+2e, 4h+2e+1 of G = Va^H Vb ----
    v2f Go[2][8];
    #pragma unroll
    for (int i = 0; i < 2; ++i)
        #pragma unroll
        for (int j = 0; j < 8; ++j) Go[i][j] = (v2f){0.f, 0.f};

    #pragma unroll 2
    for (int m = 0; m < 16; ++m) {
        float4 va4 = *(const float4*)&sva[pa][m * 8 + 4 * h + 2 * e];
        v2f a0 = {va4.x, va4.y};
        v2f a1 = {va4.z, va4.w};
        v2f vb[8];
        #pragma unroll
        for (int jj = 0; jj < 4; ++jj) {
            float4 b4 = *(const float4*)&svb[pb][m * 8 + 2 * jj];
            vb[2 * jj]     = (v2f){b4.x, b4.y};
            vb[2 * jj + 1] = (v2f){b4.z, b4.w};
        }
        #pragma unroll
        for (int j = 0; j < 8; ++j) {
            Go[0][j] = cfma_conj(a0, vb[j], Go[0][j]);
            Go[1][j] = cfma_conj(a1, vb[j], Go[1][j]);
        }
    }

    // ---- exchange 2 rows with delta-partner (xor 2) via DPP ----
    v2f Gp[2][8];
    #pragma unroll
    for (int i = 0; i < 2; ++i)
        #pragma unroll
        for (int j = 0; j < 8; ++j) {
            Gp[i][j].x = dpp_xor2(Go[i][j].x);
            Gp[i][j].y = dpp_xor2(Go[i][j].y);
        }

    // ---- rs init: delta = (+1,...,+1, sgn_e) ----
    const float sgn = 1.0f - 2.0f * (float)e;
    const v2f sgnv = {sgn, sgn};
    v2f rs[4];
    #pragma unroll
    for (int r = 0; r < 2; ++r) {
        {
            v2f s = ((Go[r][0] + Go[r][1]) + (Go[r][2] + Go[r][3]))
                  + ((Go[r][4] + Go[r][5]) + Go[r][6]);
            rs[r] = sgnv * Go[r][7] + s;
        }
        {
            v2f s = ((Gp[r][0] + Gp[r][1]) + (Gp[r][2] + Gp[r][3]))
                  + ((Gp[r][4] + Gp[r][5]) + Gp[r][6]);
            rs[2 + r] = sgnv * Gp[r][7] + s;
        }
    }

    v2f acc;

#define TREE(OUT) do {                                                \
        v2f t01 = cmul(rs[0], rs[1]);                                 \
        v2f t23 = cmul(rs[2], rs[3]);                                 \
        v2f half_ = cmul(t01, t23);                                   \
        v2f oth;                                                      \
        oth.x = dpp_xor1(half_.x);                                    \
        oth.y = dpp_xor1(half_.y);                                    \
        OUT = cmul(half_, oth);                                       \
    } while (0)

#define UPD(J, S) do {                                                \
        const v2f sv = {(S), (S)};                                    \
        rs[0] = sv * Go[0][J] + rs[0];                                \
        rs[1] = sv * Go[1][J] + rs[1];                                \
        rs[2] = sv * Gp[0][J] + rs[2];                                \
        rs[3] = sv * Gp[1][J] + rs[3];                                \
    } while (0)

#define TERM(TS) do {                                                 \
        v2f fullp; TREE(fullp);                                       \
        const v2f tv = {(TS), (TS)};                                  \
        acc = tv * fullp + acc;                                       \
    } while (0)

    TREE(acc);                              // t=0, sign +
    UPD(1, -2.f); TERM(-1.f);               // t=1
    UPD(2, -2.f); TERM( 1.f);               // t=2
    UPD(1,  2.f); TERM(-1.f);               // t=3
    UPD(3, -2.f); TERM( 1.f);               // t=4
    UPD(1, -2.f); TERM(-1.f);               // t=5
    UPD(2,  2.f); TERM( 1.f);               // t=6
    UPD(1,  2.f); TERM(-1.f);               // t=7
    UPD(4, -2.f); TERM( 1.f);               // t=8
    UPD(1, -2.f); TERM(-1.f);               // t=9
    UPD(2, -2.f); TERM( 1.f);               // t=10
    UPD(1,  2.f); TERM(-1.f);               // t=11
    UPD(3,  2.f); TERM( 1.f);               // t=12
    UPD(1, -2.f); TERM(-1.f);               // t=13
    UPD(2,  2.f); TERM( 1.f);               // t=14
    UPD(1,  2.f); TERM(-1.f);               // t=15
    UPD(5, -2.f); TERM( 1.f);               // t=16
    UPD(1, -2.f); TERM(-1.f);               // t=17
    UPD(2, -2.f); TERM( 1.f);               // t=18
    UPD(1,  2.f); TERM(-1.f);               // t=19
    UPD(3, -2.f); TERM( 1.f);               // t=20
    UPD(1, -2.f); TERM(-1.f);               // t=21
    UPD(2,  2.f); TERM( 1.f);               // t=22
    UPD(1,  2.f); TERM(-1.f);               // t=23
    UPD(4,  2.f); TERM( 1.f);               // t=24
    UPD(1, -2.f); TERM(-1.f);               // t=25
    UPD(2, -2.f); TERM( 1.f);               // t=26
    UPD(1,  2.f); TERM(-1.f);               // t=27
    UPD(3,  2.f); TERM( 1.f);               // t=28
    UPD(1, -2.f); TERM(-1.f);               // t=29
    UPD(2,  2.f); TERM( 1.f);               // t=30
    UPD(1,  2.f); TERM(-1.f);               // t=31
    UPD(6, -2.f); TERM( 1.f);               // t=32
    UPD(1, -2.f); TERM(-1.f);               // t=33
    UPD(2, -2.f); TERM( 1.f);               // t=34
    UPD(1,  2.f); TERM(-1.f);               // t=35
    UPD(3, -2.f); TERM( 1.f);               // t=36
    UPD(1, -2.f); TERM(-1.f);               // t=37
    UPD(2,  2.f); TERM( 1.f);               // t=38
    UPD(1,  2.f); TERM(-1.f);               // t=39
    UPD(4, -2.f); TERM( 1.f);               // t=40
    UPD(1, -2.f); TERM(-1.f);               // t=41
    UPD(2, -2.f); TERM( 1.f);               // t=42
    UPD(1,  2.f); TERM(-1.f);               // t=43
    UPD(3,  2.f); TERM( 1.f);               // t=44
    UPD(1, -2.f); TERM(-1.f);               // t=45
    UPD(2,  2.f); TERM( 1.f);               // t=46
    UPD(1,  2.f); TERM(-1.f);               // t=47
    UPD(5,  2.f); TERM( 1.f);               // t=48
    UPD(1, -2.f); TERM(-1.f);               // t=49
    UPD(2, -2.f); TERM( 1.f);               // t=50
    UPD(1,  2.f); TERM(-1.f);               // t=51
    UPD(3, -2.f); TERM( 1.f);               // t=52
    UPD(1, -2.f); TERM(-1.f);               // t=53
    UPD(2,  2.f); TERM( 1.f);               // t=54
    UPD(1,  2.f); TERM(-1.f);               // t=55
    UPD(4,  2.f); TERM( 1.f);               // t=56
    UPD(1, -2.f); TERM(-1.f);               // t=57
    UPD(2, -2.f); TERM( 1.f);               // t=58
    UPD(1,  2.f); TERM(-1.f);               // t=59
    UPD(3,  2.f); TERM( 1.f);               // t=60
    UPD(1, -2.f); TERM(-1.f);               // t=61
    UPD(2,  2.f); TERM( 1.f);               // t=62
    UPD(1,  2.f); TERM(-1.f);               // t=63
#undef UPD
#undef TERM
#undef TREE

    // fold delta7 sign, then combine the two delta-halves (xor 2, DPP)
    float ax = sgn * acc.x, ay = sgn * acc.y;
    ax += dpp_xor2(ax);
    ay += dpp_xor2(ay);

    if (sub == 0) {
        const int a = ta * 8 + pa;
        const int b = tb * 8 + pb;
        float K = fmaf(ax, ax, ay * ay) * (1.0f / 16384.0f);
        if (a == b) K = 1.0f;
        outK[a * 256 + b] = K;
        outK[b * 256 + a] = K;   // Hermitian symmetry
    }
}

extern "C" void kernel_launch(void* const* d_in, const int* in_sizes, int n_in,
                              void* d_out, int out_size, void* d_ws, size_t ws_size,
                              hipStream_t stream) {
    const float* x    = (const float*)d_in[0];   // 256*64
    const float* W    = (const float*)d_in[1];   // 120*64
    const float* bias = (const float*)d_in[2];   // 120
    float* out     = (float*)d_out;
    float* out_emb = out;              // 256*120
    float* outK    = out + NS * EMB;   // 256*256
    float2* Vws    = (float2*)d_ws;    // 256*16*8 float2 = 256 KB

    emb_v_kernel<<<NS, 128, 0, stream>>>(x, W, bias, out_emb, Vws);
    perm_kernel<<<528, 256, 0, stream>>>(Vws, outK);
}